// Round 8
// baseline (135.615 us; speedup 1.0000x reference)
//
#include <hip/hip_runtime.h>
#include <hip/hip_bf16.h>
#include <math.h>

#define H_ 14
#define W_ 14
#define HW_ 196
#define CIN_ 1024
#define CMID_ 256
#define NCLS_ 27
#define NB_ 16
#define ROIS_ 980
#define M_ 3136
#define FEAT_ 2304
#define NROI_ (NB_ * ROIS_)   // 15680

typedef unsigned short u16;
typedef __attribute__((ext_vector_type(8))) short bf16x8;
typedef __attribute__((ext_vector_type(4))) float f32x4;

__device__ __forceinline__ float bf2f(u16 u) {
    union { unsigned int i; float f; } x; x.i = ((unsigned int)u) << 16; return x.f;
}
__device__ __forceinline__ u16 f2bf(float f) {
    __hip_bfloat16 h = __float2bfloat16(f);
    return *reinterpret_cast<u16*>(&h);
}

// ---------------- prep: flat fp32 -> bf16 ----------------
__global__ __launch_bounds__(256) void k_f32_to_bf16(const float* __restrict__ in,
                                                     u16* __restrict__ out) {
    int i = blockIdx.x * 256 + threadIdx.x;
    out[i] = f2bf(in[i]);
}

// ---------------- prep: wfc [27][2304 CHW] -> bf16 [32][2304 bin-major], zero-pad ----------------
__global__ __launch_bounds__(256) void k_prep_wfc(const float* __restrict__ wfc,
                                                  u16* __restrict__ wfcb) {
    int idx = blockIdx.x * 256 + threadIdx.x;       // cls*2304 + k, k = bin*256 + c
    int cls = idx / FEAT_;
    int k = idx - cls * FEAT_;
    int c = k & 255, bin = k >> 8;
    float v = (cls < NCLS_) ? wfc[cls * FEAT_ + c * 9 + bin] : 0.0f;
    wfcb[idx] = f2bf(v);
}

// ---------------- K0: NCHW fp32 -> NHWC bf16, LDS-tiled (both sides coalesced) -------
// block = (batch, 64-channel tile): reads 64x196 contiguous fp32, writes bf16
// rows of 64 consecutive channels (128B/wave).
__global__ __launch_bounds__(256) void k_nchw_to_nhwc(const float* __restrict__ in,
                                                      u16* __restrict__ out) {
    __shared__ float lds[64][197];   // +1 pad: write-phase reads ci-major, 2-way only
    const int bid = blockIdx.x;
    const int b = bid >> 4, c0 = (bid & 15) << 6;
    const int t = threadIdx.x;
    const float* src = in + ((size_t)b * CIN_ + c0) * HW_;
    #pragma unroll
    for (int it = 0; it < 49; ++it) {
        int idx = it * 256 + t;               // 0..12543, contiguous read
        int ci = idx / 196;
        int hw = idx - ci * 196;
        lds[ci][hw] = src[idx];
    }
    __syncthreads();
    u16* dst = out + (size_t)b * HW_ * CIN_ + c0;
    #pragma unroll
    for (int it = 0; it < 49; ++it) {
        int idx = it * 256 + t;
        int hw = idx >> 6, ci = idx & 63;
        dst[(size_t)hw * CIN_ + ci] = f2bf(lds[ci][hw]);
    }
}

// ---------------- K1: conv1 GEMM 128x128 tile, BK=64, swizzled LDS + BN -> bf16 -------
// A[M,K] bf16, Bw[N,K] bf16 (both row-major K-contig). 4 waves in 2x2, each wave
// 64x64 out (4x4 frags of 16x16x32). LDS [128 rows][64 k] bf16 with 16B-chunk XOR
// swizzle (k8 ^= row&7) on ds_write and the same XOR on ds_read -> conflict-free.
// Next K-tile global loads issue before the MFMA block (latency under compute).
__global__ __launch_bounds__(256) void k_gemm1(
    const u16* __restrict__ A, const u16* __restrict__ Bw,
    const float* __restrict__ gg, const float* __restrict__ bb,
    const float* __restrict__ mm, const float* __restrict__ vv,
    u16* __restrict__ outp)
{
    __shared__ u16 As[128 * 64];
    __shared__ u16 Bs[128 * 64];
    const int row0 = blockIdx.y * 128, col0 = blockIdx.x * 128;
    const int t = threadIdx.x, w = t >> 6, lane = t & 63;
    const int wr = (w >> 1) * 64, wcn = (w & 1) * 64;
    const int fr = lane & 15, fkb = (lane >> 4) * 16;   // frag k-offset in bytes
    f32x4 acc[4][4] = {};

    int crow[4], ck8[4], cdst[4];
    #pragma unroll
    for (int j = 0; j < 4; ++j) {
        int c = (w * 4 + j) * 64 + lane;      // chunk 0..1023 (16B chunks)
        crow[j] = c >> 3; ck8[j] = c & 7;
        cdst[j] = crow[j] * 128 + (ck8[j] ^ (crow[j] & 7)) * 16;   // swizzled dest byte
    }
    uint4 aR[4], bR[4];
    #pragma unroll
    for (int j = 0; j < 4; ++j) {
        int rowA = min(row0 + crow[j], M_ - 1);
        aR[j] = *reinterpret_cast<const uint4*>(A + (size_t)rowA * CIN_ + ck8[j] * 8);
        bR[j] = *reinterpret_cast<const uint4*>(Bw + (size_t)(col0 + crow[j]) * CIN_ + ck8[j] * 8);
    }
    for (int kt = 0; kt < 16; ++kt) {
        #pragma unroll
        for (int j = 0; j < 4; ++j) {
            *reinterpret_cast<uint4*>((char*)As + cdst[j]) = aR[j];
            *reinterpret_cast<uint4*>((char*)Bs + cdst[j]) = bR[j];
        }
        __syncthreads();
        if (kt < 15) {
            const int k0 = (kt + 1) * 64;
            #pragma unroll
            for (int j = 0; j < 4; ++j) {
                int rowA = min(row0 + crow[j], M_ - 1);
                aR[j] = *reinterpret_cast<const uint4*>(A + (size_t)rowA * CIN_ + k0 + ck8[j] * 8);
                bR[j] = *reinterpret_cast<const uint4*>(Bw + (size_t)(col0 + crow[j]) * CIN_ + k0 + ck8[j] * 8);
            }
        }
        #pragma unroll
        for (int kk = 0; kk < 2; ++kk) {       // two K=32 steps
            const int kkB = kk * 64;           // byte offset of K-step
            bf16x8 af[4], bf[4];
            #pragma unroll
            for (int mi = 0; mi < 4; ++mi) {
                int row = wr + mi * 16 + fr;
                int byt = (row * 128 + fkb + kkB) ^ ((row & 7) << 4);
                af[mi] = *reinterpret_cast<bf16x8*>((char*)As + byt);
            }
            #pragma unroll
            for (int ni = 0; ni < 4; ++ni) {
                int row = wcn + ni * 16 + fr;
                int byt = (row * 128 + fkb + kkB) ^ ((row & 7) << 4);
                bf[ni] = *reinterpret_cast<bf16x8*>((char*)Bs + byt);
            }
            #pragma unroll
            for (int mi = 0; mi < 4; ++mi)
                #pragma unroll
                for (int ni = 0; ni < 4; ++ni)
                    acc[mi][ni] = __builtin_amdgcn_mfma_f32_16x16x32_bf16(af[mi], bf[ni], acc[mi][ni], 0, 0, 0);
        }
        __syncthreads();
    }
    #pragma unroll
    for (int ni = 0; ni < 4; ++ni) {
        int col = col0 + wcn + ni * 16 + fr;
        float sc = gg[col] * rsqrtf(vv[col] + 1e-5f);
        float bi = bb[col] - mm[col] * sc;
        #pragma unroll
        for (int mi = 0; mi < 4; ++mi) {
            #pragma unroll
            for (int rgi = 0; rgi < 4; ++rgi) {
                int row = row0 + wr + mi * 16 + (lane >> 4) * 4 + rgi;
                if (row < M_)
                    outp[(size_t)row * CIN_ + col] = f2bf(acc[mi][ni][rgi] * sc + bi);
            }
        }
    }
}

// ---------------- K2: conv2 GEMM (64x64 tile) + BN epilogue -> fp32 ----------------
template<bool OUT_F32>
__global__ __launch_bounds__(256) void k_gemm_bn(
    const u16* __restrict__ A, const u16* __restrict__ Bw,
    const float* __restrict__ gg, const float* __restrict__ bb,
    const float* __restrict__ mm, const float* __restrict__ vv,
    void* __restrict__ outp, int N, int K)
{
    __shared__ u16 As[64][40];
    __shared__ u16 Bs[64][40];
    const int row0 = blockIdx.y * 64, col0 = blockIdx.x * 64;
    const int t = threadIdx.x;
    const int lr = t >> 2, lk = (t & 3) * 8;
    const int wave = t >> 6, lane = t & 63;
    const int wr = (wave >> 1) * 32, wc = (wave & 1) * 32;
    const int fr = lane & 15, fk = (lane >> 4) * 8;
    f32x4 acc[2][2] = {};
    const u16* Aptr = A + (size_t)(row0 + lr) * K + lk;
    const u16* Bptr = Bw + (size_t)(col0 + lr) * K + lk;
    for (int k0 = 0; k0 < K; k0 += 32) {
        *reinterpret_cast<uint4*>(&As[lr][lk]) = *reinterpret_cast<const uint4*>(Aptr + k0);
        *reinterpret_cast<uint4*>(&Bs[lr][lk]) = *reinterpret_cast<const uint4*>(Bptr + k0);
        __syncthreads();
        bf16x8 a0 = *reinterpret_cast<bf16x8*>(&As[wr + fr][fk]);
        bf16x8 a1 = *reinterpret_cast<bf16x8*>(&As[wr + 16 + fr][fk]);
        bf16x8 b0 = *reinterpret_cast<bf16x8*>(&Bs[wc + fr][fk]);
        bf16x8 b1 = *reinterpret_cast<bf16x8*>(&Bs[wc + 16 + fr][fk]);
        acc[0][0] = __builtin_amdgcn_mfma_f32_16x16x32_bf16(a0, b0, acc[0][0], 0, 0, 0);
        acc[0][1] = __builtin_amdgcn_mfma_f32_16x16x32_bf16(a0, b1, acc[0][1], 0, 0, 0);
        acc[1][0] = __builtin_amdgcn_mfma_f32_16x16x32_bf16(a1, b0, acc[1][0], 0, 0, 0);
        acc[1][1] = __builtin_amdgcn_mfma_f32_16x16x32_bf16(a1, b1, acc[1][1], 0, 0, 0);
        __syncthreads();
    }
    #pragma unroll
    for (int ni = 0; ni < 2; ++ni) {
        int col = col0 + wc + ni * 16 + fr;
        float sc = gg[col] * rsqrtf(vv[col] + 1e-5f);
        float bi = bb[col] - mm[col] * sc;
        #pragma unroll
        for (int mi = 0; mi < 2; ++mi) {
            #pragma unroll
            for (int rgi = 0; rgi < 4; ++rgi) {
                int row = row0 + wr + mi * 16 + (lane >> 4) * 4 + rgi;
                float v = acc[mi][ni][rgi] * sc + bi;
                if (OUT_F32) ((float*)outp)[(size_t)row * N + col] = v;
                else         ((u16*)outp)[(size_t)row * N + col] = f2bf(v);
            }
        }
    }
}

// ---------------- K3a: roi_align via separable window weights ----------------
__global__ __launch_bounds__(256) void k_roi_feats(
    const float* __restrict__ boxes, const float* __restrict__ fmap,
    u16* __restrict__ feats)
{
    const int t = threadIdx.x, wv = t >> 6, lane = t & 63;
    const int r = blockIdx.x * 4 + wv;
    const int b = r / ROIS_;
    const float* bxp = boxes + (size_t)r * 4;
    float x1 = bxp[0], y1 = bxp[1];
    float rw = fmaxf(bxp[2] - x1, 1.0f), rh = fmaxf(bxp[3] - y1, 1.0f);
    float sx = rw * (1.0f / 3.0f), sy = rh * (1.0f / 3.0f);
    const float OFFS[6] = {0.25f, 0.75f, 1.25f, 1.75f, 2.25f, 2.75f};

    int xl[6], xh[6], yl[6], yh[6];
    float lx[6], hx[6], ly[6], hy[6];
    #pragma unroll
    for (int i = 0; i < 6; ++i) {
        float xx = fmaxf(x1 + OFFS[i] * sx, 0.0f);
        xl[i] = min((int)xx, 13); xh[i] = min(xl[i] + 1, 13);
        float xv = (xl[i] == 13) ? 13.0f : xx;
        lx[i] = xv - (float)xl[i]; hx[i] = 1.0f - lx[i];
        float yy = fmaxf(y1 + OFFS[i] * sy, 0.0f);
        yl[i] = min((int)yy, 13); yh[i] = min(yl[i] + 1, 13);
        float yv = (yl[i] == 13) ? 13.0f : yy;
        ly[i] = yv - (float)yl[i]; hy[i] = 1.0f - ly[i];
    }
    const int xc0 = min(xl[0], 8), yr0 = min(yl[0], 8);

    float WX[3][6], WY[3][6];
    #pragma unroll
    for (int bi = 0; bi < 3; ++bi)
        #pragma unroll
        for (int c = 0; c < 6; ++c) { WX[bi][c] = 0.0f; WY[bi][c] = 0.0f; }
    #pragma unroll
    for (int i = 0; i < 6; ++i) {
        const int bi = i >> 1;
        #pragma unroll
        for (int c = 0; c < 6; ++c) {
            WX[bi][c] += (xl[i] - xc0 == c ? hx[i] : 0.0f)
                       + (xh[i] - xc0 == c ? lx[i] : 0.0f);
            WY[bi][c] += (yl[i] - yr0 == c ? hy[i] : 0.0f)
                       + (yh[i] - yr0 == c ? ly[i] : 0.0f);
        }
    }

    const float* base = fmap + ((size_t)b * HW_ + yr0 * 14 + xc0) * CMID_ + lane * 4;
    f32x4 pooled[3][3] = {};
    #pragma unroll
    for (int rr = 0; rr < 6; ++rr) {
        const float* rp = base + rr * (14 * CMID_);
        f32x4 P[6];
        #pragma unroll
        for (int c = 0; c < 6; ++c)
            P[c] = *reinterpret_cast<const f32x4*>(rp + c * CMID_);
        f32x4 xin[3] = {};
        #pragma unroll
        for (int c = 0; c < 6; ++c) {
            #pragma unroll
            for (int bxx = 0; bxx < 3; ++bxx)
                xin[bxx] += P[c] * WX[bxx][c];
        }
        #pragma unroll
        for (int by = 0; by < 3; ++by)
            #pragma unroll
            for (int bxx = 0; bxx < 3; ++bxx)
                pooled[by][bxx] += xin[bxx] * WY[by][rr];
    }

    u16* fo = feats + (size_t)r * FEAT_ + lane * 4;
    #pragma unroll
    for (int by = 0; by < 3; ++by) {
        #pragma unroll
        for (int bxx = 0; bxx < 3; ++bxx) {
            const int bin = by * 3 + bxx;
            f32x4 p = pooled[by][bxx] * 0.25f;
            ushort4 s;
            s.x = f2bf(p[0]); s.y = f2bf(p[1]); s.z = f2bf(p[2]); s.w = f2bf(p[3]);
            *reinterpret_cast<ushort4*>(fo + (size_t)bin * 256) = s;
        }
    }
}

// ---------------- K3b: FC GEMM  out[NROI,27] = feats[NROI,2304] * wfcb[32,2304]^T + bfc ----
__global__ __launch_bounds__(256) void k_fc(
    const u16* __restrict__ feats, const u16* __restrict__ wfcb,
    const float* __restrict__ bfc, float* __restrict__ out)
{
    __shared__ u16 As[64][72];
    __shared__ u16 Bs[32][72];
    const int row0 = blockIdx.x * 64;
    const int t = threadIdx.x, wave = t >> 6, lane = t & 63;
    const int fr = lane & 15, fk = (lane >> 4) * 8;
    const int ar = t >> 2, ak = (t & 3) * 8;
    const int br = t >> 3, bk = (t & 7) * 8;
    f32x4 acc[2] = {};
    const u16* Ap = feats + (size_t)(row0 + ar) * FEAT_ + ak;
    const u16* Bp = wfcb + (size_t)br * FEAT_ + bk;
    uint4 a0n = *reinterpret_cast<const uint4*>(Ap);
    uint4 a1n = *reinterpret_cast<const uint4*>(Ap + 32);
    uint4 b0n = *reinterpret_cast<const uint4*>(Bp);
    for (int k0 = 0; k0 < FEAT_; k0 += 64) {
        *reinterpret_cast<uint4*>(&As[ar][ak]) = a0n;
        *reinterpret_cast<uint4*>(&As[ar][ak + 32]) = a1n;
        *reinterpret_cast<uint4*>(&Bs[br][bk]) = b0n;
        __syncthreads();
        if (k0 + 64 < FEAT_) {
            a0n = *reinterpret_cast<const uint4*>(Ap + k0 + 64);
            a1n = *reinterpret_cast<const uint4*>(Ap + k0 + 96);
            b0n = *reinterpret_cast<const uint4*>(Bp + k0 + 64);
        }
        #pragma unroll
        for (int kk = 0; kk < 64; kk += 32) {
            bf16x8 a  = *reinterpret_cast<bf16x8*>(&As[wave * 16 + fr][fk + kk]);
            bf16x8 b0 = *reinterpret_cast<bf16x8*>(&Bs[fr][fk + kk]);
            bf16x8 b1 = *reinterpret_cast<bf16x8*>(&Bs[16 + fr][fk + kk]);
            acc[0] = __builtin_amdgcn_mfma_f32_16x16x32_bf16(a, b0, acc[0], 0, 0, 0);
            acc[1] = __builtin_amdgcn_mfma_f32_16x16x32_bf16(a, b1, acc[1], 0, 0, 0);
        }
        __syncthreads();
    }
    #pragma unroll
    for (int ni = 0; ni < 2; ++ni) {
        int col = ni * 16 + fr;
        if (col < NCLS_) {
            float bi = bfc[col];
            #pragma unroll
            for (int rgi = 0; rgi < 4; ++rgi) {
                int row = row0 + wave * 16 + (lane >> 4) * 4 + rgi;
                out[(size_t)row * NCLS_ + col] = acc[ni][rgi] + bi;
            }
        }
    }
}

extern "C" void kernel_launch(void* const* d_in, const int* in_sizes, int n_in,
                              void* d_out, int out_size, void* d_ws, size_t ws_size,
                              hipStream_t stream) {
    const float* boxes   = (const float*)d_in[0];
    const float* fmap_in = (const float*)d_in[1];
    const float* w1 = (const float*)d_in[2];
    const float* g1 = (const float*)d_in[3];
    const float* b1 = (const float*)d_in[4];
    const float* m1 = (const float*)d_in[5];
    const float* v1 = (const float*)d_in[6];
    const float* w2 = (const float*)d_in[7];
    const float* g2 = (const float*)d_in[8];
    const float* b2 = (const float*)d_in[9];
    const float* m2 = (const float*)d_in[10];
    const float* v2 = (const float*)d_in[11];
    const float* wfc = (const float*)d_in[12];
    const float* bfc = (const float*)d_in[13];

    char* ws = (char*)d_ws;
    u16*   Anhwc     = (u16*)(ws + 0);               //  6,422,528 B
    float* fmapw_f32 = (float*)(ws + 0);             //  3,211,264 B (aliases Anhwc; dead after conv1)
    u16*   h         = (u16*)(ws + 6422528);         //  6,422,528 B
    u16*   w1b       = (u16*)(ws + 14450688);        //  2,097,152 B
    u16*   w2b       = (u16*)(ws + 16547840);        //    524,288 B
    u16*   wfcb      = (u16*)(ws + 17072128);        //    147,456 B
    u16*   feats     = (u16*)(ws + 17219584);        // 72,253,440 B  (total ~89.5 MB)

    hipLaunchKernelGGL(k_f32_to_bf16, dim3((CIN_ * CIN_) / 256), dim3(256), 0, stream,
                       w1, w1b);
    hipLaunchKernelGGL(k_f32_to_bf16, dim3((CMID_ * CIN_) / 256), dim3(256), 0, stream,
                       w2, w2b);
    hipLaunchKernelGGL(k_prep_wfc, dim3((32 * FEAT_) / 256), dim3(256), 0, stream,
                       wfc, wfcb);
    hipLaunchKernelGGL(k_nchw_to_nhwc, dim3(NB_ * 16), dim3(256), 0, stream,
                       fmap_in, Anhwc);
    hipLaunchKernelGGL(k_gemm1, dim3(CIN_ / 128, 25), dim3(256), 0, stream,
                       Anhwc, w1b, g1, b1, m1, v1, h);
    hipLaunchKernelGGL((k_gemm_bn<true>), dim3(CMID_ / 64, M_ / 64), dim3(256), 0, stream,
                       h, w2b, g2, b2, m2, v2, (void*)fmapw_f32, CMID_, CIN_);
    hipLaunchKernelGGL(k_roi_feats, dim3(NROI_ / 4), dim3(256), 0, stream,
                       boxes, fmapw_f32, feats);
    hipLaunchKernelGGL(k_fc, dim3(NROI_ / 64), dim3(256), 0, stream,
                       feats, wfcb, bfc, (float*)d_out);
}

// Round 9
// 105.800 us; speedup vs baseline: 1.2818x; 1.2818x over previous
//
#include <hip/hip_runtime.h>
#include <hip/hip_bf16.h>
#include <math.h>

#define H_ 14
#define W_ 14
#define HW_ 196
#define CIN_ 1024
#define CMID_ 256
#define NCLS_ 27
#define NB_ 16
#define ROIS_ 980
#define M_ 3136
#define FEAT_ 2304
#define NROI_ (NB_ * ROIS_)   // 15680

typedef unsigned short u16;
typedef __attribute__((ext_vector_type(8))) short bf16x8;
typedef __attribute__((ext_vector_type(4))) float f32x4;

__device__ __forceinline__ float bf2f(u16 u) {
    union { unsigned int i; float f; } x; x.i = ((unsigned int)u) << 16; return x.f;
}
__device__ __forceinline__ u16 f2bf(float f) {
    __hip_bfloat16 h = __float2bfloat16(f);
    return *reinterpret_cast<u16*>(&h);
}

// ---------------- prep: flat fp32 -> bf16 ----------------
__global__ __launch_bounds__(256) void k_f32_to_bf16(const float* __restrict__ in,
                                                     u16* __restrict__ out) {
    int i = blockIdx.x * 256 + threadIdx.x;
    out[i] = f2bf(in[i]);
}

// ---------------- prep: wfc [27][2304 CHW] -> bf16 [32][2304 bin-major], zero-pad ----------------
__global__ __launch_bounds__(256) void k_prep_wfc(const float* __restrict__ wfc,
                                                  u16* __restrict__ wfcb) {
    int idx = blockIdx.x * 256 + threadIdx.x;       // cls*2304 + k, k = bin*256 + c
    int cls = idx / FEAT_;
    int k = idx - cls * FEAT_;
    int c = k & 255, bin = k >> 8;
    float v = (cls < NCLS_) ? wfc[cls * FEAT_ + c * 9 + bin] : 0.0f;
    wfcb[idx] = f2bf(v);
}

// ---------------- K0: NCHW fp32 -> NHWC bf16, LDS-tiled (both sides coalesced) -------
__global__ __launch_bounds__(256) void k_nchw_to_nhwc(const float* __restrict__ in,
                                                      u16* __restrict__ out) {
    __shared__ float lds[64][197];
    const int bid = blockIdx.x;
    const int b = bid >> 4, c0 = (bid & 15) << 6;
    const int t = threadIdx.x;
    const float* src = in + ((size_t)b * CIN_ + c0) * HW_;
    #pragma unroll
    for (int it = 0; it < 49; ++it) {
        int idx = it * 256 + t;               // contiguous read
        int ci = idx / 196;
        int hw = idx - ci * 196;
        lds[ci][hw] = src[idx];
    }
    __syncthreads();
    u16* dst = out + (size_t)b * HW_ * CIN_ + c0;
    #pragma unroll
    for (int it = 0; it < 49; ++it) {
        int idx = it * 256 + t;
        int hw = idx >> 6, ci = idx & 63;
        dst[(size_t)hw * CIN_ + ci] = f2bf(lds[ci][hw]);
    }
}

// ---------------- K1: conv1 GEMM 64x64 tile, BK=64, reg-prefetch + BN -> bf16 --------
// 784 blocks (~3 blocks/CU, ~37% occupancy for latency hiding — R8's 128^2 tile gave
// 200 blocks -> 7% occ -> latency-bound at 52us). 4 waves 2x2, each 32x32 out.
// XCD-chunked bijective swizzle: 784 = 8*98, blocks with same M-row land together.
__global__ __launch_bounds__(256) void k_gemm1(
    const u16* __restrict__ A, const u16* __restrict__ Bw,
    const float* __restrict__ gg, const float* __restrict__ bb,
    const float* __restrict__ mm, const float* __restrict__ vv,
    u16* __restrict__ outp)
{
    __shared__ u16 As[64][72];
    __shared__ u16 Bs[64][72];
    const int bid = blockIdx.x;
    const int swz = (bid & 7) * 98 + (bid >> 3);    // bijective: 784 = 8*98
    const int row0 = (swz >> 4) * 64, col0 = (swz & 15) * 64;
    const int t = threadIdx.x, w = t >> 6, lane = t & 63;
    const int wr = (w >> 1) * 32, wc = (w & 1) * 32;
    const int fr = lane & 15, fk = (lane >> 4) * 8;
    const int sr = t >> 2, sk = (t & 3) * 16;       // staging: 4 thr/row, 2x16B each
    f32x4 acc[2][2] = {};

    const u16* Ap = A + (size_t)(row0 + sr) * CIN_ + sk;
    const u16* Bp = Bw + (size_t)(col0 + sr) * CIN_ + sk;
    uint4 a0 = *reinterpret_cast<const uint4*>(Ap);
    uint4 a1 = *reinterpret_cast<const uint4*>(Ap + 8);
    uint4 b0 = *reinterpret_cast<const uint4*>(Bp);
    uint4 b1 = *reinterpret_cast<const uint4*>(Bp + 8);
    for (int kt = 0; kt < 16; ++kt) {
        *reinterpret_cast<uint4*>(&As[sr][sk]) = a0;
        *reinterpret_cast<uint4*>(&As[sr][sk + 8]) = a1;
        *reinterpret_cast<uint4*>(&Bs[sr][sk]) = b0;
        *reinterpret_cast<uint4*>(&Bs[sr][sk + 8]) = b1;
        __syncthreads();
        if (kt < 15) {
            const int k0 = (kt + 1) * 64;
            a0 = *reinterpret_cast<const uint4*>(Ap + k0);
            a1 = *reinterpret_cast<const uint4*>(Ap + k0 + 8);
            b0 = *reinterpret_cast<const uint4*>(Bp + k0);
            b1 = *reinterpret_cast<const uint4*>(Bp + k0 + 8);
        }
        #pragma unroll
        for (int kk = 0; kk < 2; ++kk) {
            const int ko = fk + kk * 32;
            bf16x8 af0 = *reinterpret_cast<bf16x8*>(&As[wr + fr][ko]);
            bf16x8 af1 = *reinterpret_cast<bf16x8*>(&As[wr + 16 + fr][ko]);
            bf16x8 bf0 = *reinterpret_cast<bf16x8*>(&Bs[wc + fr][ko]);
            bf16x8 bf1 = *reinterpret_cast<bf16x8*>(&Bs[wc + 16 + fr][ko]);
            acc[0][0] = __builtin_amdgcn_mfma_f32_16x16x32_bf16(af0, bf0, acc[0][0], 0, 0, 0);
            acc[0][1] = __builtin_amdgcn_mfma_f32_16x16x32_bf16(af0, bf1, acc[0][1], 0, 0, 0);
            acc[1][0] = __builtin_amdgcn_mfma_f32_16x16x32_bf16(af1, bf0, acc[1][0], 0, 0, 0);
            acc[1][1] = __builtin_amdgcn_mfma_f32_16x16x32_bf16(af1, bf1, acc[1][1], 0, 0, 0);
        }
        __syncthreads();
    }
    #pragma unroll
    for (int ni = 0; ni < 2; ++ni) {
        int col = col0 + wc + ni * 16 + fr;
        float sc = gg[col] * rsqrtf(vv[col] + 1e-5f);
        float bi = bb[col] - mm[col] * sc;
        #pragma unroll
        for (int mi = 0; mi < 2; ++mi) {
            #pragma unroll
            for (int rgi = 0; rgi < 4; ++rgi) {
                int row = row0 + wr + mi * 16 + (lane >> 4) * 4 + rgi;
                outp[(size_t)row * CIN_ + col] = f2bf(acc[mi][ni][rgi] * sc + bi);
            }
        }
    }
}

// ---------------- K2: conv2 GEMM (64x64 tile) + BN epilogue ----------------
template<bool OUT_F32>
__global__ __launch_bounds__(256) void k_gemm_bn(
    const u16* __restrict__ A, const u16* __restrict__ Bw,
    const float* __restrict__ gg, const float* __restrict__ bb,
    const float* __restrict__ mm, const float* __restrict__ vv,
    void* __restrict__ outp, int N, int K)
{
    __shared__ u16 As[64][40];
    __shared__ u16 Bs[64][40];
    const int row0 = blockIdx.y * 64, col0 = blockIdx.x * 64;
    const int t = threadIdx.x;
    const int lr = t >> 2, lk = (t & 3) * 8;
    const int wave = t >> 6, lane = t & 63;
    const int wr = (wave >> 1) * 32, wc = (wave & 1) * 32;
    const int fr = lane & 15, fk = (lane >> 4) * 8;
    f32x4 acc[2][2] = {};
    const u16* Aptr = A + (size_t)(row0 + lr) * K + lk;
    const u16* Bptr = Bw + (size_t)(col0 + lr) * K + lk;
    for (int k0 = 0; k0 < K; k0 += 32) {
        *reinterpret_cast<uint4*>(&As[lr][lk]) = *reinterpret_cast<const uint4*>(Aptr + k0);
        *reinterpret_cast<uint4*>(&Bs[lr][lk]) = *reinterpret_cast<const uint4*>(Bptr + k0);
        __syncthreads();
        bf16x8 a0 = *reinterpret_cast<bf16x8*>(&As[wr + fr][fk]);
        bf16x8 a1 = *reinterpret_cast<bf16x8*>(&As[wr + 16 + fr][fk]);
        bf16x8 b0 = *reinterpret_cast<bf16x8*>(&Bs[wc + fr][fk]);
        bf16x8 b1 = *reinterpret_cast<bf16x8*>(&Bs[wc + 16 + fr][fk]);
        acc[0][0] = __builtin_amdgcn_mfma_f32_16x16x32_bf16(a0, b0, acc[0][0], 0, 0, 0);
        acc[0][1] = __builtin_amdgcn_mfma_f32_16x16x32_bf16(a0, b1, acc[0][1], 0, 0, 0);
        acc[1][0] = __builtin_amdgcn_mfma_f32_16x16x32_bf16(a1, b0, acc[1][0], 0, 0, 0);
        acc[1][1] = __builtin_amdgcn_mfma_f32_16x16x32_bf16(a1, b1, acc[1][1], 0, 0, 0);
        __syncthreads();
    }
    #pragma unroll
    for (int ni = 0; ni < 2; ++ni) {
        int col = col0 + wc + ni * 16 + fr;
        float sc = gg[col] * rsqrtf(vv[col] + 1e-5f);
        float bi = bb[col] - mm[col] * sc;
        #pragma unroll
        for (int mi = 0; mi < 2; ++mi) {
            #pragma unroll
            for (int rgi = 0; rgi < 4; ++rgi) {
                int row = row0 + wr + mi * 16 + (lane >> 4) * 4 + rgi;
                float v = acc[mi][ni][rgi] * sc + bi;
                if (OUT_F32) ((float*)outp)[(size_t)row * N + col] = v;
                else         ((u16*)outp)[(size_t)row * N + col] = f2bf(v);
            }
        }
    }
}

// ---------------- K3a: roi_align via separable window weights ----------------
__global__ __launch_bounds__(256) void k_roi_feats(
    const float* __restrict__ boxes, const float* __restrict__ fmap,
    u16* __restrict__ feats)
{
    const int t = threadIdx.x, wv = t >> 6, lane = t & 63;
    const int r = blockIdx.x * 4 + wv;
    const int b = r / ROIS_;
    const float* bxp = boxes + (size_t)r * 4;
    float x1 = bxp[0], y1 = bxp[1];
    float rw = fmaxf(bxp[2] - x1, 1.0f), rh = fmaxf(bxp[3] - y1, 1.0f);
    float sx = rw * (1.0f / 3.0f), sy = rh * (1.0f / 3.0f);
    const float OFFS[6] = {0.25f, 0.75f, 1.25f, 1.75f, 2.25f, 2.75f};

    int xl[6], xh[6], yl[6], yh[6];
    float lx[6], hx[6], ly[6], hy[6];
    #pragma unroll
    for (int i = 0; i < 6; ++i) {
        float xx = fmaxf(x1 + OFFS[i] * sx, 0.0f);
        xl[i] = min((int)xx, 13); xh[i] = min(xl[i] + 1, 13);
        float xv = (xl[i] == 13) ? 13.0f : xx;
        lx[i] = xv - (float)xl[i]; hx[i] = 1.0f - lx[i];
        float yy = fmaxf(y1 + OFFS[i] * sy, 0.0f);
        yl[i] = min((int)yy, 13); yh[i] = min(yl[i] + 1, 13);
        float yv = (yl[i] == 13) ? 13.0f : yy;
        ly[i] = yv - (float)yl[i]; hy[i] = 1.0f - ly[i];
    }
    const int xc0 = min(xl[0], 8), yr0 = min(yl[0], 8);

    float WX[3][6], WY[3][6];
    #pragma unroll
    for (int bi = 0; bi < 3; ++bi)
        #pragma unroll
        for (int c = 0; c < 6; ++c) { WX[bi][c] = 0.0f; WY[bi][c] = 0.0f; }
    #pragma unroll
    for (int i = 0; i < 6; ++i) {
        const int bi = i >> 1;
        #pragma unroll
        for (int c = 0; c < 6; ++c) {
            WX[bi][c] += (xl[i] - xc0 == c ? hx[i] : 0.0f)
                       + (xh[i] - xc0 == c ? lx[i] : 0.0f);
            WY[bi][c] += (yl[i] - yr0 == c ? hy[i] : 0.0f)
                       + (yh[i] - yr0 == c ? ly[i] : 0.0f);
        }
    }

    const float* base = fmap + ((size_t)b * HW_ + yr0 * 14 + xc0) * CMID_ + lane * 4;
    f32x4 pooled[3][3] = {};
    #pragma unroll
    for (int rr = 0; rr < 6; ++rr) {
        const float* rp = base + rr * (14 * CMID_);
        f32x4 P[6];
        #pragma unroll
        for (int c = 0; c < 6; ++c)
            P[c] = *reinterpret_cast<const f32x4*>(rp + c * CMID_);
        f32x4 xin[3] = {};
        #pragma unroll
        for (int c = 0; c < 6; ++c) {
            #pragma unroll
            for (int bxx = 0; bxx < 3; ++bxx)
                xin[bxx] += P[c] * WX[bxx][c];
        }
        #pragma unroll
        for (int by = 0; by < 3; ++by)
            #pragma unroll
            for (int bxx = 0; bxx < 3; ++bxx)
                pooled[by][bxx] += xin[bxx] * WY[by][rr];
    }

    u16* fo = feats + (size_t)r * FEAT_ + lane * 4;
    #pragma unroll
    for (int by = 0; by < 3; ++by) {
        #pragma unroll
        for (int bxx = 0; bxx < 3; ++bxx) {
            const int bin = by * 3 + bxx;
            f32x4 p = pooled[by][bxx] * 0.25f;
            ushort4 s;
            s.x = f2bf(p[0]); s.y = f2bf(p[1]); s.z = f2bf(p[2]); s.w = f2bf(p[3]);
            *reinterpret_cast<ushort4*>(fo + (size_t)bin * 256) = s;
        }
    }
}

// ---------------- K3b: FC GEMM  out[NROI,27] = feats[NROI,2304] * wfcb[32,2304]^T + bfc ----
__global__ __launch_bounds__(256) void k_fc(
    const u16* __restrict__ feats, const u16* __restrict__ wfcb,
    const float* __restrict__ bfc, float* __restrict__ out)
{
    __shared__ u16 As[64][72];
    __shared__ u16 Bs[32][72];
    const int row0 = blockIdx.x * 64;
    const int t = threadIdx.x, wave = t >> 6, lane = t & 63;
    const int fr = lane & 15, fk = (lane >> 4) * 8;
    const int ar = t >> 2, ak = (t & 3) * 8;
    const int br = t >> 3, bk = (t & 7) * 8;
    f32x4 acc[2] = {};
    const u16* Ap = feats + (size_t)(row0 + ar) * FEAT_ + ak;
    const u16* Bp = wfcb + (size_t)br * FEAT_ + bk;
    uint4 a0n = *reinterpret_cast<const uint4*>(Ap);
    uint4 a1n = *reinterpret_cast<const uint4*>(Ap + 32);
    uint4 b0n = *reinterpret_cast<const uint4*>(Bp);
    for (int k0 = 0; k0 < FEAT_; k0 += 64) {
        *reinterpret_cast<uint4*>(&As[ar][ak]) = a0n;
        *reinterpret_cast<uint4*>(&As[ar][ak + 32]) = a1n;
        *reinterpret_cast<uint4*>(&Bs[br][bk]) = b0n;
        __syncthreads();
        if (k0 + 64 < FEAT_) {
            a0n = *reinterpret_cast<const uint4*>(Ap + k0 + 64);
            a1n = *reinterpret_cast<const uint4*>(Ap + k0 + 96);
            b0n = *reinterpret_cast<const uint4*>(Bp + k0 + 64);
        }
        #pragma unroll
        for (int kk = 0; kk < 64; kk += 32) {
            bf16x8 a  = *reinterpret_cast<bf16x8*>(&As[wave * 16 + fr][fk + kk]);
            bf16x8 b0 = *reinterpret_cast<bf16x8*>(&Bs[fr][fk + kk]);
            bf16x8 b1 = *reinterpret_cast<bf16x8*>(&Bs[16 + fr][fk + kk]);
            acc[0] = __builtin_amdgcn_mfma_f32_16x16x32_bf16(a, b0, acc[0], 0, 0, 0);
            acc[1] = __builtin_amdgcn_mfma_f32_16x16x32_bf16(a, b1, acc[1], 0, 0, 0);
        }
        __syncthreads();
    }
    #pragma unroll
    for (int ni = 0; ni < 2; ++ni) {
        int col = ni * 16 + fr;
        if (col < NCLS_) {
            float bi = bfc[col];
            #pragma unroll
            for (int rgi = 0; rgi < 4; ++rgi) {
                int row = row0 + wave * 16 + (lane >> 4) * 4 + rgi;
                out[(size_t)row * NCLS_ + col] = acc[ni][rgi] + bi;
            }
        }
    }
}

extern "C" void kernel_launch(void* const* d_in, const int* in_sizes, int n_in,
                              void* d_out, int out_size, void* d_ws, size_t ws_size,
                              hipStream_t stream) {
    const float* boxes   = (const float*)d_in[0];
    const float* fmap_in = (const float*)d_in[1];
    const float* w1 = (const float*)d_in[2];
    const float* g1 = (const float*)d_in[3];
    const float* b1 = (const float*)d_in[4];
    const float* m1 = (const float*)d_in[5];
    const float* v1 = (const float*)d_in[6];
    const float* w2 = (const float*)d_in[7];
    const float* g2 = (const float*)d_in[8];
    const float* b2 = (const float*)d_in[9];
    const float* m2 = (const float*)d_in[10];
    const float* v2 = (const float*)d_in[11];
    const float* wfc = (const float*)d_in[12];
    const float* bfc = (const float*)d_in[13];

    char* ws = (char*)d_ws;
    u16*   Anhwc     = (u16*)(ws + 0);               //  6,422,528 B
    float* fmapw_f32 = (float*)(ws + 0);             //  3,211,264 B (aliases Anhwc; dead after conv1)
    u16*   h         = (u16*)(ws + 6422528);         //  6,422,528 B
    u16*   w1b       = (u16*)(ws + 14450688);        //  2,097,152 B
    u16*   w2b       = (u16*)(ws + 16547840);        //    524,288 B
    u16*   wfcb      = (u16*)(ws + 17072128);        //    147,456 B
    u16*   feats     = (u16*)(ws + 17219584);        // 72,253,440 B  (total ~89.5 MB)

    hipLaunchKernelGGL(k_f32_to_bf16, dim3((CIN_ * CIN_) / 256), dim3(256), 0, stream,
                       w1, w1b);
    hipLaunchKernelGGL(k_f32_to_bf16, dim3((CMID_ * CIN_) / 256), dim3(256), 0, stream,
                       w2, w2b);
    hipLaunchKernelGGL(k_prep_wfc, dim3((32 * FEAT_) / 256), dim3(256), 0, stream,
                       wfc, wfcb);
    hipLaunchKernelGGL(k_nchw_to_nhwc, dim3(NB_ * 16), dim3(256), 0, stream,
                       fmap_in, Anhwc);
    hipLaunchKernelGGL(k_gemm1, dim3(784), dim3(256), 0, stream,
                       Anhwc, w1b, g1, b1, m1, v1, h);
    hipLaunchKernelGGL((k_gemm_bn<true>), dim3(CMID_ / 64, M_ / 64), dim3(256), 0, stream,
                       h, w2b, g2, b2, m2, v2, (void*)fmapw_f32, CMID_, CIN_);
    hipLaunchKernelGGL(k_roi_feats, dim3(NROI_ / 4), dim3(256), 0, stream,
                       boxes, fmapw_f32, feats);
    hipLaunchKernelGGL(k_fc, dim3(NROI_ / 64), dim3(256), 0, stream,
                       feats, wfcb, bfc, (float*)d_out);
}